// Round 3
// baseline (262.277 us; speedup 1.0000x reference)
//
#include <hip/hip_runtime.h>

namespace {

constexpr int Bn      = 64;
constexpr int QN      = 16;
constexpr int Dn      = 64;
constexpr int DVn     = 64;
constexpr int KVn     = 16384;
constexpr int MAX_SPLITS = 32;
constexpr int TILE    = 64;             // keys per tile
constexpr int THREADS = 256;

// LDS row pitches (floats). KP/AP = 68 floats = 272 B = 17*16B: odd multiple of
// 16B -> b128 row-per-lane reads spread across bank quads (measured: 0 bank
// conflicts). VP = 64: column reads are lane==bank, conflict-free.
constexpr int KP = 68;   // K tile row pitch (row holds 64 floats)
constexpr int SP = 20;   // S tile row pitch (row holds 16 floats)
constexpr int QP = 64;   // Q row pitch (broadcast reads)
constexpr int AP = 68;   // A row pitch (row holds 64 floats)
constexpr int VP = 64;   // V row pitch

constexpr float SCALE = 0.125f * 1.4426950408889634f;  // (1/sqrt(64)) * log2(e)

__device__ __forceinline__ float dot4(float4 a, float4 b, float acc) {
    return fmaf(a.x, b.x, fmaf(a.y, b.y, fmaf(a.z, b.z, fmaf(a.w, b.w, acc))));
}

__global__ __launch_bounds__(THREADS, 3)
void inv_attn_part(const float* __restrict__ query,
                   const float* __restrict__ key,
                   const float* __restrict__ value,
                   float* __restrict__ pout,   // [B][splits][QN][DVn]
                   float* __restrict__ pden,   // [B][splits][QN]
                   int ntiles)
{
    __shared__ __align__(16) float q_lds[QN * QP];
    __shared__ __align__(16) float k_lds[TILE * KP];
    __shared__ __align__(16) float s_lds[TILE * SP];
    __shared__ __align__(16) float a_lds[QN * AP];
    __shared__ __align__(16) float v_lds[TILE * VP];

    const int tid  = threadIdx.x;
    const int lane = tid & 63;
    const int w    = tid >> 6;      // wave id 0..3; wave owns q = 4w..4w+3
    const int spl  = blockIdx.x;
    const int splits = gridDim.x;
    const int b    = blockIdx.y;
    const int key_base = spl * ntiles * TILE;
    const int q0 = 4 * w;

    // this thread's 4 staging slots: rows/chunks for idx = i*256+tid
    const int sr0 = tid >> 4;           // i=0 row (0..15), c = tid&15
    const int sc  = tid & 15;

    // ---- stage Q, pre-scaled so QK^T lands in log2 domain ----
    {
        float4 v = *reinterpret_cast<const float4*>(
            query + ((size_t)b * QN + sr0) * Dn + sc * 4);
        v.x *= SCALE; v.y *= SCALE; v.z *= SCALE; v.w *= SCALE;
        *reinterpret_cast<float4*>(&q_lds[sr0 * QP + sc * 4]) = v;
    }

    float acc0 = 0.f, acc1 = 0.f, acc2 = 0.f, acc3 = 0.f;  // out[q0+j][dv=lane]
    float den0 = 0.f, den1 = 0.f, den2 = 0.f, den3 = 0.f;

    // ---- prologue: prefetch tile 0 into registers (global->VGPR survives
    //      barriers: no LDS visibility, compiler won't vmcnt(0)-drain it) ----
    float4 kreg[4], vreg[4];
    {
        const int kt = key_base;
        #pragma unroll
        for (int i = 0; i < 4; ++i) {
            const int r = sr0 + i * 16;
            const size_t grow = ((size_t)b * KVn + kt + r) * Dn + sc * 4;
            kreg[i] = *reinterpret_cast<const float4*>(key + grow);
            vreg[i] = *reinterpret_cast<const float4*>(value + grow);
        }
    }

    for (int t = 0; t < ntiles; ++t) {
        __syncthreads();   // A: prev tile's k/v/s fully consumed (covers Q too)

        // ---- commit prefetched registers to LDS ----
        #pragma unroll
        for (int i = 0; i < 4; ++i) {
            const int r = sr0 + i * 16;
            *reinterpret_cast<float4*>(&k_lds[r * KP + sc * 4]) = kreg[i];
            *reinterpret_cast<float4*>(&v_lds[r * VP + sc * 4]) = vreg[i];
        }
        __syncthreads();   // B: tiles visible to all waves

        // ---- issue prefetch of tile t+1 (hidden under compute below) ----
        if (t + 1 < ntiles) {
            const int kt = key_base + (t + 1) * TILE;
            #pragma unroll
            for (int i = 0; i < 4; ++i) {
                const int r = sr0 + i * 16;
                const size_t grow = ((size_t)b * KVn + kt + r) * Dn + sc * 4;
                kreg[i] = *reinterpret_cast<const float4*>(key + grow);
                vreg[i] = *reinterpret_cast<const float4*>(value + grow);
            }
        }

        // ---- QK^T: lane = key row, wave computes its 4 q's ----
        float s0 = 0.f, s1 = 0.f, s2 = 0.f, s3 = 0.f;
        #pragma unroll
        for (int d0 = 0; d0 < Dn; d0 += 4) {
            const float4 kv = *reinterpret_cast<const float4*>(&k_lds[lane * KP + d0]);
            const float4 qa = *reinterpret_cast<const float4*>(&q_lds[(q0 + 0) * QP + d0]);
            const float4 qb = *reinterpret_cast<const float4*>(&q_lds[(q0 + 1) * QP + d0]);
            const float4 qc = *reinterpret_cast<const float4*>(&q_lds[(q0 + 2) * QP + d0]);
            const float4 qd = *reinterpret_cast<const float4*>(&q_lds[(q0 + 3) * QP + d0]);
            s0 = dot4(kv, qa, s0);
            s1 = dot4(kv, qb, s1);
            s2 = dot4(kv, qc, s2);
            s3 = dot4(kv, qd, s3);
        }
        *reinterpret_cast<float4*>(&s_lds[lane * SP + w * 4]) =
            make_float4(s0, s1, s2, s3);
        __syncthreads();   // C: S columns from all waves visible

        // ---- softmax over q (16 values) per key; redundant across waves ----
        const float4 e0 = *reinterpret_cast<const float4*>(&s_lds[lane * SP + 0]);
        const float4 e1 = *reinterpret_cast<const float4*>(&s_lds[lane * SP + 4]);
        const float4 e2 = *reinterpret_cast<const float4*>(&s_lds[lane * SP + 8]);
        const float4 e3 = *reinterpret_cast<const float4*>(&s_lds[lane * SP + 12]);
        float m = fmaxf(fmaxf(fmaxf(e0.x, e0.y), fmaxf(e0.z, e0.w)),
                        fmaxf(fmaxf(e1.x, e1.y), fmaxf(e1.z, e1.w)));
        m = fmaxf(m, fmaxf(fmaxf(fmaxf(e2.x, e2.y), fmaxf(e2.z, e2.w)),
                           fmaxf(fmaxf(e3.x, e3.y), fmaxf(e3.z, e3.w))));
        float4 x0, x1, x2, x3;
        x0.x = exp2f(e0.x - m); x0.y = exp2f(e0.y - m); x0.z = exp2f(e0.z - m); x0.w = exp2f(e0.w - m);
        x1.x = exp2f(e1.x - m); x1.y = exp2f(e1.y - m); x1.z = exp2f(e1.z - m); x1.w = exp2f(e1.w - m);
        x2.x = exp2f(e2.x - m); x2.y = exp2f(e2.y - m); x2.z = exp2f(e2.z - m); x2.w = exp2f(e2.w - m);
        x3.x = exp2f(e3.x - m); x3.y = exp2f(e3.y - m); x3.z = exp2f(e3.z - m); x3.w = exp2f(e3.w - m);
        const float sumq = (x0.x + x0.y + x0.z + x0.w) + (x1.x + x1.y + x1.z + x1.w)
                         + (x2.x + x2.y + x2.z + x2.w) + (x3.x + x3.y + x3.z + x3.w);
        const float inv = 1.0f / sumq;
        const float4 mine = (w == 0) ? x0 : (w == 1) ? x1 : (w == 2) ? x2 : x3;
        const float a0 = mine.x * inv, a1 = mine.y * inv,
                    a2 = mine.z * inv, a3 = mine.w * inv;
        // a_lds rows q0..q0+3 are PRIVATE to this wave: same-wave write->read,
        // no barrier needed (compiler inserts lgkmcnt).
        a_lds[(q0 + 0) * AP + lane] = a0;
        a_lds[(q0 + 1) * AP + lane] = a1;
        a_lds[(q0 + 2) * AP + lane] = a2;
        a_lds[(q0 + 3) * AP + lane] = a3;
        den0 += a0; den1 += a1; den2 += a2; den3 += a3;

        // ---- PV: wave owns (its 4 q's) x (dv = lane); loop keys ----
        #pragma unroll
        for (int k0 = 0; k0 < TILE; k0 += 4) {
            const float4 a0v = *reinterpret_cast<const float4*>(&a_lds[(q0 + 0) * AP + k0]);
            const float4 a1v = *reinterpret_cast<const float4*>(&a_lds[(q0 + 1) * AP + k0]);
            const float4 a2v = *reinterpret_cast<const float4*>(&a_lds[(q0 + 2) * AP + k0]);
            const float4 a3v = *reinterpret_cast<const float4*>(&a_lds[(q0 + 3) * AP + k0]);
            {
                const float vv = v_lds[(k0 + 0) * VP + lane];
                acc0 = fmaf(a0v.x, vv, acc0); acc1 = fmaf(a1v.x, vv, acc1);
                acc2 = fmaf(a2v.x, vv, acc2); acc3 = fmaf(a3v.x, vv, acc3);
            }
            {
                const float vv = v_lds[(k0 + 1) * VP + lane];
                acc0 = fmaf(a0v.y, vv, acc0); acc1 = fmaf(a1v.y, vv, acc1);
                acc2 = fmaf(a2v.y, vv, acc2); acc3 = fmaf(a3v.y, vv, acc3);
            }
            {
                const float vv = v_lds[(k0 + 2) * VP + lane];
                acc0 = fmaf(a0v.z, vv, acc0); acc1 = fmaf(a1v.z, vv, acc1);
                acc2 = fmaf(a2v.z, vv, acc2); acc3 = fmaf(a3v.z, vv, acc3);
            }
            {
                const float vv = v_lds[(k0 + 3) * VP + lane];
                acc0 = fmaf(a0v.w, vv, acc0); acc1 = fmaf(a1v.w, vv, acc1);
                acc2 = fmaf(a2v.w, vv, acc2); acc3 = fmaf(a3v.w, vv, acc3);
            }
        }
    }

    // ---- write partial PV outputs (coalesced, 256B rows) ----
    const size_t obase = (((size_t)b * splits + spl) * QN) * DVn;
    pout[obase + (q0 + 0) * DVn + lane] = acc0;
    pout[obase + (q0 + 1) * DVn + lane] = acc1;
    pout[obase + (q0 + 2) * DVn + lane] = acc2;
    pout[obase + (q0 + 3) * DVn + lane] = acc3;

    // ---- wave-reduce denom partials, write 4 scalars ----
    #pragma unroll
    for (int off = 32; off > 0; off >>= 1) {
        den0 += __shfl_down(den0, off, 64);
        den1 += __shfl_down(den1, off, 64);
        den2 += __shfl_down(den2, off, 64);
        den3 += __shfl_down(den3, off, 64);
    }
    if (lane == 0) {
        const size_t dbase = ((size_t)b * splits + spl) * QN;
        pden[dbase + q0 + 0] = den0;
        pden[dbase + q0 + 1] = den1;
        pden[dbase + q0 + 2] = den2;
        pden[dbase + q0 + 3] = den3;
    }
}

__global__ __launch_bounds__(256)
void inv_attn_reduce(const float* __restrict__ pout,
                     const float* __restrict__ pden,
                     float* __restrict__ out,
                     int splits)
{
    const int gid = blockIdx.x * blockDim.x + threadIdx.x;   // 0..65535
    const int dv = gid & 63;
    const int q  = (gid >> 6) & (QN - 1);
    const int b  = gid >> 10;
    float sum = 0.f, den = 0.f;
    #pragma unroll 8
    for (int sp = 0; sp < splits; ++sp) {
        sum += pout[(((size_t)b * splits + sp) * QN + q) * DVn + dv];
        den += pden[((size_t)b * splits + sp) * QN + q];
    }
    out[gid] = sum / (den + 1e-8f);
}

}  // namespace

extern "C" void kernel_launch(void* const* d_in, const int* in_sizes, int n_in,
                              void* d_out, int out_size, void* d_ws, size_t ws_size,
                              hipStream_t stream) {
    const float* query = (const float*)d_in[0];
    const float* key   = (const float*)d_in[1];
    const float* value = (const float*)d_in[2];
    float* out = (float*)d_out;

    // Largest split count whose partials fit in d_ws (deterministic).
    int splits = MAX_SPLITS;
    auto need = [](int s) {
        return (size_t)Bn * s * QN * DVn * sizeof(float)
             + (size_t)Bn * s * QN * sizeof(float);
    };
    while (splits > 1 && need(splits) > ws_size) splits >>= 1;

    float* pout = (float*)d_ws;
    float* pden = pout + (size_t)Bn * splits * QN * DVn;

    const int ntiles = KVn / (splits * TILE);   // tiles per block

    dim3 grid1(splits, Bn);
    inv_attn_part<<<grid1, THREADS, 0, stream>>>(query, key, value, pout, pden, ntiles);

    const int total = Bn * QN * DVn;            // 65536
    inv_attn_reduce<<<total / 256, 256, 0, stream>>>(pout, pden, out, splits);
}

// Round 4
// 105.548 us; speedup vs baseline: 2.4849x; 2.4849x over previous
//
#include <hip/hip_runtime.h>

namespace {

typedef float f32x4 __attribute__((ext_vector_type(4)));
typedef short bf16x8 __attribute__((ext_vector_type(8)));

constexpr int Bn = 64, QN = 16, Dn = 64, DVn = 64, KVn = 16384;
constexpr int MAX_SPLITS = 32;
constexpr int TILE    = 64;     // keys per tile
constexpr int THREADS = 256;    // 4 waves
constexpr int AP   = 68;        // probs LDS row pitch (floats): 272B = 17*16B
constexpr int VROW = 160;       // vT row pitch in BYTES: 128B data + 32B pad

constexpr float SCALE = 0.125f * 1.4426950408889634f;  // 1/sqrt(64) * log2(e)

__device__ __forceinline__ unsigned cvt_pk_bf16(float a, float b) {
    unsigned r;
    asm("v_cvt_pk_bf16_f32 %0, %1, %2" : "=v"(r) : "v"(a), "v"(b));
    return r;
}

union FragU { unsigned u[4]; bf16x8 v; };

// split 8 fp32 into hi/lo bf16x8 fragments (hi = rne-bf16, lo = bf16(x - hi))
__device__ __forceinline__ void split8(const float x[8], bf16x8& hi, bf16x8& lo) {
    FragU uh, ul;
#pragma unroll
    for (int p = 0; p < 4; ++p) {
        const float a = x[2 * p], b2 = x[2 * p + 1];
        const unsigned h = cvt_pk_bf16(a, b2);
        uh.u[p] = h;
        const float ha = __uint_as_float(h << 16);
        const float hb = __uint_as_float(h & 0xffff0000u);
        ul.u[p] = cvt_pk_bf16(a - ha, b2 - hb);
    }
    hi = uh.v; lo = ul.v;
}

__global__ __launch_bounds__(THREADS, 4)
void inv_attn_part(const float* __restrict__ query,
                   const float* __restrict__ key,
                   const float* __restrict__ value,
                   float* __restrict__ pout,   // [B][splits][QN][DVn]
                   float* __restrict__ pden,   // [B][splits][QN]
                   int ntiles)
{
    // LDS: only the P-transpose buffer (fp32) and V^T (bf16, swizzled), dbuf'd.
    __shared__ __align__(16) float a_s[2][QN * AP];        // 2 x 4.35 KB
    __shared__ __align__(16) char  vT[2][DVn * VROW];      // 2 x 10.0 KB
    __shared__ float den_buf[4][QN];

    const int tid  = threadIdx.x;
    const int lane = tid & 63;
    const int w    = tid >> 6;          // wave id: owns keys w*16.. (QK) / dv w*16.. (PV)
    const int l15  = lane & 15;
    const int g    = lane >> 4;         // k-chunk group for MFMA frags
    const int spl  = blockIdx.x;
    const int splits = gridDim.x;
    const int b    = blockIdx.y;
    const int kt0  = spl * ntiles * TILE;

    // ---- hoist Q fragments into registers (A-frag: row=l15, k = ks*32+g*8+j) ----
    bf16x8 qhi[2], qlo[2];
    {
        const float* qp = query + ((size_t)b * QN + l15) * Dn + g * 8;
#pragma unroll
        for (int ks = 0; ks < 2; ++ks) {
            const float4 u0 = *reinterpret_cast<const float4*>(qp + ks * 32);
            const float4 u1 = *reinterpret_cast<const float4*>(qp + ks * 32 + 4);
            float x[8] = { u0.x * SCALE, u0.y * SCALE, u0.z * SCALE, u0.w * SCALE,
                           u1.x * SCALE, u1.y * SCALE, u1.z * SCALE, u1.w * SCALE };
            split8(x, qhi[ks], qlo[ks]);
        }
    }

    f32x4 oacc = {0.f, 0.f, 0.f, 0.f};          // O[q=g*4+r][dv=w*16+l15]
    float den0 = 0.f, den1 = 0.f, den2 = 0.f, den3 = 0.f;

    // V staging map: thread stages key=(tid>>4)+16i, dv=(tid&15)*4+j
    const int vkey = tid >> 4;
    const int vdv0 = (tid & 15) * 4;
    const int vsw  = ((tid & 15) & 7) << 4;     // XOR swizzle = ((dv>>2)&7)<<4

    // K fragment source: this lane's key row (+ g*8 element offset)
    const float* kbase = key   + ((size_t)b * KVn + kt0 + w * 16 + l15) * Dn + g * 8;
    const float* vbase = value + ((size_t)b * KVn + kt0 + vkey) * Dn + vdv0;

    for (int t = 0; t < ntiles; ++t) {
        const int buf = t & 1;

        // ---- stage V tile: fp32 -> bf16, transposed into vT[dv][key] (swizzled) ----
        float4 vv[4];
#pragma unroll
        for (int i = 0; i < 4; ++i)
            vv[i] = *reinterpret_cast<const float4*>(vbase + ((size_t)t * TILE + 16 * i) * Dn);
#pragma unroll
        for (int i = 0; i < 4; ++i) {
            const int kk = vkey + 16 * i;
#pragma unroll
            for (int j = 0; j < 4; ++j) {
                const float xv = (j == 0) ? vv[i].x : (j == 1) ? vv[i].y
                                : (j == 2) ? vv[i].z : vv[i].w;
                const unsigned uu = cvt_pk_bf16(xv, xv);
                *reinterpret_cast<short*>(&vT[buf][(vdv0 + j) * VROW + ((2 * kk) ^ vsw)]) =
                    (short)uu;
            }
        }

        // ---- QK^T via MFMA: S[q][key], A=Q (regs), B=K (global, hi/lo split) ----
        f32x4 sacc = {0.f, 0.f, 0.f, 0.f};
#pragma unroll
        for (int ks = 0; ks < 2; ++ks) {
            const float4 ka = *reinterpret_cast<const float4*>(kbase + (size_t)t * TILE * Dn + ks * 32);
            const float4 kb = *reinterpret_cast<const float4*>(kbase + (size_t)t * TILE * Dn + ks * 32 + 4);
            float x[8] = { ka.x, ka.y, ka.z, ka.w, kb.x, kb.y, kb.z, kb.w };
            bf16x8 khi, klo;
            split8(x, khi, klo);
            sacc = __builtin_amdgcn_mfma_f32_16x16x32_bf16(qhi[ks], khi, sacc, 0, 0, 0);
            sacc = __builtin_amdgcn_mfma_f32_16x16x32_bf16(qhi[ks], klo, sacc, 0, 0, 0);
            sacc = __builtin_amdgcn_mfma_f32_16x16x32_bf16(qlo[ks], khi, sacc, 0, 0, 0);
        }

        // ---- softmax over q (16) for key = kt0 + t*64 + w*16 + l15 ----
        float m = fmaxf(fmaxf(sacc[0], sacc[1]), fmaxf(sacc[2], sacc[3]));
        m = fmaxf(m, __shfl_xor(m, 16, 64));
        m = fmaxf(m, __shfl_xor(m, 32, 64));
        float p0 = exp2f(sacc[0] - m), p1 = exp2f(sacc[1] - m);
        float p2 = exp2f(sacc[2] - m), p3 = exp2f(sacc[3] - m);
        float s4 = p0 + p1 + p2 + p3;
        s4 += __shfl_xor(s4, 16, 64);
        s4 += __shfl_xor(s4, 32, 64);
        const float inv = 1.0f / s4;
        p0 *= inv; p1 *= inv; p2 *= inv; p3 *= inv;
        const int kloc = w * 16 + l15;
        a_s[buf][(g * 4 + 0) * AP + kloc] = p0;
        a_s[buf][(g * 4 + 1) * AP + kloc] = p1;
        a_s[buf][(g * 4 + 2) * AP + kloc] = p2;
        a_s[buf][(g * 4 + 3) * AP + kloc] = p3;
        den0 += p0; den1 += p1; den2 += p2; den3 += p3;

        __syncthreads();   // probs + vT of tile t visible; prev-buf reads done

        // ---- PV via MFMA: O[q][dv] += P[q][key] * V[key][dv] ----
#pragma unroll
        for (int ks = 0; ks < 2; ++ks) {
            const int base = ks * 32 + g * 8;
            const float4 a0 = *reinterpret_cast<const float4*>(&a_s[buf][l15 * AP + base]);
            const float4 a1 = *reinterpret_cast<const float4*>(&a_s[buf][l15 * AP + base + 4]);
            FragU ua;
            ua.u[0] = cvt_pk_bf16(a0.x, a0.y);
            ua.u[1] = cvt_pk_bf16(a0.z, a0.w);
            ua.u[2] = cvt_pk_bf16(a1.x, a1.y);
            ua.u[3] = cvt_pk_bf16(a1.z, a1.w);
            const int dv = w * 16 + l15;
            const int gran = (((ks * 4 + g) ^ ((dv >> 2) & 7)) << 4);
            const bf16x8 vf = *reinterpret_cast<const bf16x8*>(&vT[buf][dv * VROW + gran]);
            oacc = __builtin_amdgcn_mfma_f32_16x16x32_bf16(ua.v, vf, oacc, 0, 0, 0);
        }
    }

    // ---- write partial outputs: O[q=g*4+r][dv=w*16+l15] ----
    const size_t obase = (((size_t)b * splits + spl) * QN) * DVn;
    const int dv = w * 16 + l15;
    pout[obase + (g * 4 + 0) * DVn + dv] = oacc[0];
    pout[obase + (g * 4 + 1) * DVn + dv] = oacc[1];
    pout[obase + (g * 4 + 2) * DVn + dv] = oacc[2];
    pout[obase + (g * 4 + 3) * DVn + dv] = oacc[3];

    // ---- denominator: reduce over the 16 keys (l15) within the wave ----
#pragma unroll
    for (int off = 1; off < 16; off <<= 1) {
        den0 += __shfl_xor(den0, off, 64);
        den1 += __shfl_xor(den1, off, 64);
        den2 += __shfl_xor(den2, off, 64);
        den3 += __shfl_xor(den3, off, 64);
    }
    if (l15 == 0) {
        den_buf[w][g * 4 + 0] = den0;
        den_buf[w][g * 4 + 1] = den1;
        den_buf[w][g * 4 + 2] = den2;
        den_buf[w][g * 4 + 3] = den3;
    }
    __syncthreads();
    if (tid < QN) {
        const float d = den_buf[0][tid] + den_buf[1][tid] + den_buf[2][tid] + den_buf[3][tid];
        pden[((size_t)b * splits + spl) * QN + tid] = d;
    }
}

__global__ __launch_bounds__(256)
void inv_attn_reduce(const float* __restrict__ pout,
                     const float* __restrict__ pden,
                     float* __restrict__ out,
                     int splits)
{
    const int gid = blockIdx.x * blockDim.x + threadIdx.x;   // 0..65535
    const int dv = gid & 63;
    const int q  = (gid >> 6) & (QN - 1);
    const int b  = gid >> 10;
    float sum = 0.f, den = 0.f;
#pragma unroll 8
    for (int sp = 0; sp < splits; ++sp) {
        sum += pout[(((size_t)b * splits + sp) * QN + q) * DVn + dv];
        den += pden[((size_t)b * splits + sp) * QN + q];
    }
    out[gid] = sum / (den + 1e-8f);
}

}  // namespace

extern "C" void kernel_launch(void* const* d_in, const int* in_sizes, int n_in,
                              void* d_out, int out_size, void* d_ws, size_t ws_size,
                              hipStream_t stream) {
    const float* query = (const float*)d_in[0];
    const float* key   = (const float*)d_in[1];
    const float* value = (const float*)d_in[2];
    float* out = (float*)d_out;

    int splits = MAX_SPLITS;
    auto need = [](int s) {
        return (size_t)Bn * s * QN * DVn * sizeof(float)
             + (size_t)Bn * s * QN * sizeof(float);
    };
    while (splits > 1 && need(splits) > ws_size) splits >>= 1;

    float* pout = (float*)d_ws;
    float* pden = pout + (size_t)Bn * splits * QN * DVn;

    const int ntiles = KVn / (splits * TILE);

    dim3 grid1(splits, Bn);
    inv_attn_part<<<grid1, THREADS, 0, stream>>>(query, key, value, pout, pden, ntiles);

    const int total = Bn * QN * DVn;   // 65536
    inv_attn_reduce<<<total / 256, 256, 0, stream>>>(pout, pden, out, splits);
}